// Round 8
// baseline (268.696 us; speedup 1.0000x reference)
//
#include <hip/hip_runtime.h>

typedef unsigned short u16;
typedef unsigned int   u32;
typedef short  short8   __attribute__((ext_vector_type(8)));
typedef float  floatx4  __attribute__((ext_vector_type(4)));
typedef u16    ushortx2 __attribute__((ext_vector_type(2)));
typedef u16    ushortx4 __attribute__((ext_vector_type(4)));

__device__ __forceinline__ float bf2f(u16 u) {
  union { u32 i; float f; } v; v.i = ((u32)u) << 16; return v.f;
}
__device__ __forceinline__ u16 f2bf(float x) {
  union { float f; u32 i; } v; v.f = x;
  u32 r = v.i + 0x7FFFu + ((v.i >> 16) & 1u);   // round-to-nearest-even
  return (u16)(r >> 16);
}

#if __has_builtin(__builtin_amdgcn_exp2f)
#define EXP2F(x) __builtin_amdgcn_exp2f(x)
#else
#define EXP2F(x) __exp2f(x)
#endif

// async global->LDS, 16B per lane; LDS dest = wave-uniform base + lane*16
#define GLOAD_LDS16(gptr, lptr)                                                   \
  __builtin_amdgcn_global_load_lds(                                               \
      (const __attribute__((address_space(1))) void*)(gptr),                      \
      (__attribute__((address_space(3))) void*)(lptr), 16, 0, 0)

#define WAITV(n) asm volatile("s_waitcnt vmcnt(" #n ")" ::: "memory")
#define WAITL    asm volatile("s_waitcnt lgkmcnt(0)" ::: "memory")
#define BAR      __builtin_amdgcn_s_barrier()

// ---------------------------------------------------------------------------
// fp32 -> bf16 bulk convert, all 5 tensors in one launch (blockIdx.y selects).
// ---------------------------------------------------------------------------
__global__ __launch_bounds__(256) void cvt_all(
    const floatx4* __restrict__ x,  const floatx4* __restrict__ wq,
    const floatx4* __restrict__ wk, const floatx4* __restrict__ wv,
    const floatx4* __restrict__ wo,
    ushortx4* __restrict__ xb, ushortx4* __restrict__ wqkv,
    ushortx4* __restrict__ wob) {
  int i = blockIdx.x * 256 + threadIdx.x;
  const floatx4* in; ushortx4* out;
  switch (blockIdx.y) {
    case 0:  in = x;  out = xb; break;
    case 1:  in = wq; out = wqkv; break;
    case 2:  in = wk; out = wqkv + (size_t)1048576; break;   // 2048*2048/4
    case 3:  in = wv; out = wqkv + (size_t)2097152; break;
    default: in = wo; out = wob; break;
  }
  floatx4 v = in[i];
  ushortx4 o;
  o.x = f2bf(v.x); o.y = f2bf(v.y); o.z = f2bf(v.z); o.w = f2bf(v.w);
  out[i] = o;
}

// ---------------------------------------------------------------------------
// 256x192 8-wave BT-GEMM, BK=64, 3-phase K-loop, counted vmcnt,
// R7: ds_reads software-pipelined ONE PHASE AHEAD of their consuming MFMAs
// (m196-style ds_read∥MFMA interleave).  Each phase now issues the NEXT
// phase's fragment reads alongside its own MFMAs; the lgkmcnt stall that
// opened every phase is gone.
//
// Frag sets (rule #20: all statically indexed; B0/B1 ping-pong via 2x
// unrolled loop):
//   afh0[4][2]  A-h0(t): read P3(t-1), consumed P1(t)
//   afh1[4][2]  A-h1(t): read P2(t) mid-MFMA, consumed P2/P3(t)
//   b01E/b01O[2][2]  B0,B1: read P3(t-1) into set (t&1), consumed P1..P3(t)
//   bfr2[2]     B2(t): read P1(t), consumed P2/P3(t)
//
// Steady-state iteration (bf=kt&1, nb=bf^1; gload FIFO g1,g2=A-h0 g3=B0
// g4=B1 g5=B2 g6,g7=A-h1):
//  P1: ST g1-3'(t+1) | vmcnt(3) -> g5-g7(t) in | BAR |
//      RD B2(t) || MFMA h0xB0, h0xB1         (consume afh0, b01[t&1])
//  P2: ST g4,5'(t+1) | BAR |
//      RD A-h1(t) || MFMA h0xB2, h1xB0
//  P3: ST g6,7'(t+1) | vmcnt(3) -> g1'-g4' in | BAR |
//      RD A-h0(t+1), B01(t+1) || MFMA h1xB1, h1xB2
// Wait coverage identical to R3 (each moved read sits after the same
// WAITV+BAR that guaranteed its rows); every ds_read is consumed by an MFMA
// before the next gload_lds write to its rows (compiler lgkm-orders).
// ---------------------------------------------------------------------------
__global__ __launch_bounds__(512, 2) void gemm256_bt(
    const u16* __restrict__ A, const u16* __restrict__ B, u16* __restrict__ C,
    int N, int K, int lda, int ldb, int ldc) {
  // bijective XCD swizzle (gridDim.x % 8 == 0)
  const int cpx = gridDim.x >> 3;
  const int wg = ((int)blockIdx.x & 7) * cpx + ((int)blockIdx.x >> 3);
  const int ntn = N / 192;
  const int m0 = (wg / ntn) << 8;
  const int n0 = (wg % ntn) * 192;

  __shared__ __align__(16) u16 As[2][256][64];
  __shared__ __align__(16) u16 Bs[2][192][64];

  const int t = threadIdx.x;
  const int lane = t & 63;
  const int wave = t >> 6;
  const int wr = wave >> 2;          // 0..1
  const int wc = wave & 3;           // 0..3
  const int quad = lane >> 4;
  const int mrow = lane & 15;
  const int sw = mrow & 7;

  // staging: per gload, wave writes 1 KiB = 8 rows x 8 segs; global col-seg
  // pre-swizzled so a linear LDS write realizes the seg-XOR layout.
  const int srow = lane >> 3;                    // 0..7
  const int gso  = ((lane & 7) ^ srow) << 3;     // u16 col offset

  const u16* gA = A + (size_t)(m0 + (wave << 3) + srow) * lda + gso;
  const u16* gB = B + (size_t)(n0 + (wave << 3) + srow) * ldb + gso;

  floatx4 acc[8][3] = {};
  short8 afh0[4][2], afh1[4][2];
  short8 b01E[2][2], b01O[2][2];
  short8 bfr2[2];

  const int NT = K >> 6;                         // K-tiles (even, >= 4)

#define ST_A(nb, h, kt)                                                        \
  do {                                                                         \
    GLOAD_LDS16(gA + (size_t)((h) * 128) * lda + ((kt) << 6),                  \
                &As[nb][(h) * 128 + (wave << 3)][0]);                          \
    GLOAD_LDS16(gA + (size_t)((h) * 128 + 64) * lda + ((kt) << 6),             \
                &As[nb][(h) * 128 + 64 + (wave << 3)][0]);                     \
  } while (0)
#define ST_B1(nb, c, kt)                                                       \
  do {                                                                         \
    GLOAD_LDS16(gB + (size_t)((c) * 64) * ldb + ((kt) << 6),                   \
                &Bs[nb][(c) * 64 + (wave << 3)][0]);                           \
  } while (0)

#define RD_AH0(bf)                                                             \
  do {                                                                         \
    _Pragma("unroll") for (int i_ = 0; i_ < 4; i_++)                           \
      _Pragma("unroll") for (int k_ = 0; k_ < 2; k_++)                         \
        afh0[i_][k_] = *(const short8*)&As[bf][(wr << 6) + (i_ << 4) + mrow]   \
                            [(((k_ << 2) | quad) ^ sw) << 3];                  \
  } while (0)
#define RD_AH1(bf)                                                             \
  do {                                                                         \
    _Pragma("unroll") for (int i_ = 0; i_ < 4; i_++)                           \
      _Pragma("unroll") for (int k_ = 0; k_ < 2; k_++)                         \
        afh1[i_][k_] = *(const short8*)&As[bf][128 + (wr << 6) + (i_ << 4) + mrow] \
                            [(((k_ << 2) | quad) ^ sw) << 3];                  \
  } while (0)
#define RD_B01(bf, DST)                                                        \
  do {                                                                         \
    _Pragma("unroll") for (int j_ = 0; j_ < 2; j_++)                           \
      _Pragma("unroll") for (int k_ = 0; k_ < 2; k_++)                         \
        DST[j_][k_] = *(const short8*)&Bs[bf][j_ * 64 + (wc << 4) + mrow]      \
                          [(((k_ << 2) | quad) ^ sw) << 3];                    \
  } while (0)
#define RD_B2(bf)                                                              \
  do {                                                                         \
    _Pragma("unroll") for (int k_ = 0; k_ < 2; k_++)                           \
      bfr2[k_] = *(const short8*)&Bs[bf][128 + (wc << 4) + mrow]               \
                     [(((k_ << 2) | quad) ^ sw) << 3];                         \
  } while (0)

  // 8 MFMA: acc[ilo..ilo+3][j] += AF x BF2  (BF2 is a short8[2])
#define MM8(AF, BF2, ilo, j)                                                   \
  do {                                                                         \
    __builtin_amdgcn_s_setprio(1);                                             \
    _Pragma("unroll") for (int k_ = 0; k_ < 2; k_++)                           \
      _Pragma("unroll") for (int i_ = 0; i_ < 4; i_++)                         \
        acc[(ilo) + i_][j] = __builtin_amdgcn_mfma_f32_16x16x32_bf16(          \
            AF[i_][k_], BF2[k_], acc[(ilo) + i_][j], 0, 0, 0);                 \
    __builtin_amdgcn_s_setprio(0);                                             \
  } while (0)

  // one K-tile, reads pipelined one phase ahead.  BC = B01 set for tile kt
  // (consumed), BN = set filled with tile kt+1's B01.
#define BODY(kt, bf, nb, BC, BN)                                               \
  do {                                                                         \
    /* P1 */                                                                   \
    ST_A(nb, 0, (kt) + 1); ST_B1(nb, 0, (kt) + 1);                             \
    WAITV(3);                                                                  \
    BAR;                                                                       \
    RD_B2(bf);                                                                 \
    MM8(afh0, BC[0], 0, 0);                                                    \
    MM8(afh0, BC[1], 0, 1);                                                    \
    /* P2 */                                                                   \
    ST_B1(nb, 1, (kt) + 1); ST_B1(nb, 2, (kt) + 1);                            \
    BAR;                                                                       \
    RD_AH1(bf);                                                                \
    MM8(afh0, bfr2, 0, 2);                                                     \
    MM8(afh1, BC[0], 4, 0);                                                    \
    /* P3 */                                                                   \
    ST_A(nb, 1, (kt) + 1);                                                     \
    WAITV(3);                                                                  \
    BAR;                                                                       \
    RD_AH0(nb); RD_B01(nb, BN);                                                \
    MM8(afh1, BC[1], 4, 1);                                                    \
    MM8(afh1, bfr2, 4, 2);                                                     \
  } while (0)

  // prologue: stage tile 0 (g1..g7); g1-g4 resident; pre-read P1 frags
  ST_A(0, 0, 0); ST_B1(0, 0, 0); ST_B1(0, 1, 0); ST_B1(0, 2, 0); ST_A(0, 1, 0);
  WAITV(3);
  BAR;
  RD_AH0(0); RD_B01(0, b01E);

  // NT-1 staged tiles: pairs keep B01 set indexing static (rule #20)
#pragma unroll 1
  for (int kt = 0; kt + 2 < NT; kt += 2) {
    BODY(kt, 0, 1, b01E, b01O);
    BODY(kt + 1, 1, 0, b01O, b01E);
  }
  BODY(NT - 2, 0, 1, b01E, b01O);

  {  // last tile (bf = 1), consumes b01O; no staging
    WAITV(0);                                  // g5,g6,g7 resident
    BAR;
    RD_B2(1);
    MM8(afh0, b01O[0], 0, 0);
    MM8(afh0, b01O[1], 0, 1);
    RD_AH1(1);
    MM8(afh0, bfr2, 0, 2);
    MM8(afh1, b01O[0], 4, 0);
    MM8(afh1, b01O[1], 4, 1);
    MM8(afh1, bfr2, 4, 2);
  }

  // epilogue. C/D layout: col = lane&15, row = quad*4 + reg
#pragma unroll
  for (int i = 0; i < 8; i++) {
    int row0 = m0 + ((i >= 4) ? 128 : 0) + (wr << 6) + ((i & 3) << 4) + (quad << 2);
#pragma unroll
    for (int j = 0; j < 3; j++) {
      int col = n0 + j * 64 + (wc << 4) + mrow;
#pragma unroll
      for (int r = 0; r < 4; r++)
        C[(size_t)(row0 + r) * ldc + col] = f2bf(acc[i][j][r]);
    }
  }
#undef ST_A
#undef ST_B1
#undef RD_AH0
#undef RD_AH1
#undef RD_B01
#undef RD_B2
#undef MM8
#undef BODY
}

// ---------------------------------------------------------------------------
// Output projection: out[m][n] = sum_k AT[m][k]*WOb[n][k], fp32 out direct.
// 128x128 tile, 256 blocks (full fill), 2 blocks/CU, 2-phase counted vmcnt.
// (R5 — unchanged this round.)
// ---------------------------------------------------------------------------
__global__ __launch_bounds__(256, 2) void gemm_out(
    const u16* __restrict__ A, const u16* __restrict__ B,
    float* __restrict__ C) {
  // bijective XCD swizzle over 256 blocks
  const int wg = ((int)blockIdx.x & 7) * 32 + ((int)blockIdx.x >> 3);
  const int m0 = (wg >> 4) << 7;
  const int n0 = (wg & 15) << 7;

  __shared__ __align__(16) u16 As[2][128][64];
  __shared__ __align__(16) u16 Bs[2][128][64];

  const int t = threadIdx.x;
  const int lane = t & 63;
  const int wave = t >> 6;           // 0..3
  const int wr = wave >> 1;          // 0..1
  const int wc = wave & 1;           // 0..1
  const int quad = lane >> 4;
  const int mrow = lane & 15;
  const int sw = mrow & 7;

  const int srow = lane >> 3;                    // 0..7
  const int gso  = ((lane & 7) ^ srow) << 3;     // pre-swizzled col seg

  const u16* gA = A + (size_t)(m0 + (wave << 3) + srow) * 2048 + gso;
  const u16* gB = B + (size_t)(n0 + (wave << 3) + srow) * 2048 + gso;

  floatx4 acc[4][4] = {};
  short8 afr[4][2], bfr[4][2];

  const int NT = 32;                             // 2048/64

#define OST_A(nb, p, kt)                                                       \
  GLOAD_LDS16(gA + (size_t)((p) * 32) * 2048 + ((kt) << 6),                    \
              &As[nb][(p) * 32 + (wave << 3)][0])
#define OST_B(nb, p, kt)                                                       \
  GLOAD_LDS16(gB + (size_t)((p) * 32) * 2048 + ((kt) << 6),                    \
              &Bs[nb][(p) * 32 + (wave << 3)][0])

#define OLDA(bf)                                                               \
  do {                                                                         \
    _Pragma("unroll") for (int i_ = 0; i_ < 4; i_++)                           \
      _Pragma("unroll") for (int kk_ = 0; kk_ < 2; kk_++)                      \
        afr[i_][kk_] = *(const short8*)&As[bf][(wr << 6) + (i_ << 4) + mrow]   \
                            [(((kk_ << 2) | quad) ^ sw) << 3];                 \
  } while (0)
#define OLDB2(bf, jlo)                                                         \
  do {                                                                         \
    _Pragma("unroll") for (int j_ = 0; j_ < 2; j_++)                           \
      _Pragma("unroll") for (int kk_ = 0; kk_ < 2; kk_++)                      \
        bfr[(jlo) + j_][kk_] =                                                 \
            *(const short8*)&Bs[bf][(wc << 6) + (((jlo) + j_) << 4) + mrow]    \
                [(((kk_ << 2) | quad) ^ sw) << 3];                             \
  } while (0)
#define OMM16(jlo)                                                             \
  do {                                                                         \
    __builtin_amdgcn_s_setprio(1);                                             \
    _Pragma("unroll") for (int kk_ = 0; kk_ < 2; kk_++)                        \
      _Pragma("unroll") for (int i_ = 0; i_ < 4; i_++)                         \
        _Pragma("unroll") for (int j_ = 0; j_ < 2; j_++)                       \
          acc[i_][(jlo) + j_] = __builtin_amdgcn_mfma_f32_16x16x32_bf16(       \
              afr[i_][kk_], bfr[(jlo) + j_][kk_], acc[i_][(jlo) + j_], 0, 0, 0);\
    __builtin_amdgcn_s_setprio(0);                                             \
  } while (0)

  // prologue: FIFO g1..g8 = A0,A1,A2,A3,B0,B2,B1,B3
  OST_A(0, 0, 0); OST_A(0, 1, 0); OST_A(0, 2, 0); OST_A(0, 3, 0);
  OST_B(0, 0, 0); OST_B(0, 2, 0); OST_B(0, 1, 0); OST_B(0, 3, 0);
  WAITV(2);                                    // g1..g6 resident for P1
  BAR;

  for (int kt = 0; kt < NT - 1; kt++) {
    const int bf = kt & 1, nb = bf ^ 1;
    // ---- P1 ----
    OLDA(bf);
    OLDB2(bf, 0);
    OST_A(nb, 0, kt + 1); OST_A(nb, 1, kt + 1);
    OST_A(nb, 2, kt + 1); OST_A(nb, 3, kt + 1);
    OST_B(nb, 0, kt + 1); OST_B(nb, 2, kt + 1);
    WAITV(6);                                  // g7,g8(kt) resident
    BAR;
    OMM16(0);
    // ---- P2 ----
    OLDB2(bf, 2);
    OST_B(nb, 1, kt + 1); OST_B(nb, 3, kt + 1);
    WAITV(2);                                  // g1'..g6' resident (next P1)
    BAR;
    OMM16(2);
  }
  {                                            // last tile, no staging
    const int bf = (NT - 1) & 1;
    OLDA(bf);
    OLDB2(bf, 0);
    WAITV(0);                                  // g7,g8 resident
    BAR;
    OMM16(0);
    OLDB2(bf, 2);
    OMM16(2);
  }

  // epilogue: fp32 direct. C/D layout: col = lane&15, row = quad*4 + reg
#pragma unroll
  for (int i = 0; i < 4; i++) {
    int row0 = m0 + (wr << 6) + (i << 4) + (quad << 2);
#pragma unroll
    for (int j = 0; j < 4; j++) {
      int col = n0 + (wc << 6) + (j << 4) + mrow;
#pragma unroll
      for (int r = 0; r < 4; r++)
        C[(size_t)(row0 + r) * 2048 + col] = acc[i][j][r];
    }
  }
#undef OST_A
#undef OST_B
#undef OLDA
#undef OLDB2
#undef OMM16
}

// ---------------------------------------------------------------------------
// Merged aux kernel: blocks [0,16384) = RoPE on Q,K; blocks [16384,17408) =
// transpose V (cols 4096..6143 of QKV, ld 6144) -> VT[d][s] (ld 2048).
// ---------------------------------------------------------------------------
__global__ __launch_bounds__(256) void rope_trans(
    u16* __restrict__ qkv, const float* __restrict__ cs,
    const float* __restrict__ sn, u16* __restrict__ vt) {
  __shared__ u16 tile[64][68];
  const int bx = blockIdx.x;
  if (bx < 16384) {
    const int isK = bx >> 13;                  // 0 = Q, 1 = K
    int idx = (bx & 8191) * 256 + threadIdx.x;
    int p = idx & 63;
    int h = (idx >> 6) & 15;
    int s = idx >> 10;
    float c  = cs[(s << 6) | p];
    float si = sn[(s << 6) | p];
    float scale = isK ? 1.0f : 0.12751743f;    // log2(e)/sqrt(128)
    size_t off = (size_t)s * 6144 + (isK ? 2048 : 0) + (h << 7) + (p << 1);
    ushortx2 eo = *(ushortx2*)(qkv + off);
    float e = bf2f(eo.x), o = bf2f(eo.y);
    ushortx2 r;
    r.x = f2bf((e * c - o * si) * scale);
    r.y = f2bf((e * si + o * c) * scale);
    *(ushortx2*)(qkv + off) = r;
  } else {
    const int b = bx - 16384;
    const u16* src = qkv + 4096;
    const int d0 = (b & 31) << 6;
    const int s0 = (b >> 5) << 6;
    const int tx = (threadIdx.x & 15) << 2;
    const int ty = threadIdx.x >> 4;
#pragma unroll
    for (int rr = 0; rr < 64; rr += 16) {
      ushortx4 v = *(const ushortx4*)(src + (size_t)(s0 + ty + rr) * 6144 + d0 + tx);
      *(ushortx4*)&tile[ty + rr][tx] = v;
    }
    __syncthreads();
#pragma unroll
    for (int rr = 0; rr < 64; rr += 16) {
      int r = ty + rr;
      ushortx4 o;
      o.x = tile[tx + 0][r]; o.y = tile[tx + 1][r];
      o.z = tile[tx + 2][r]; o.w = tile[tx + 3][r];
      *(ushortx4*)(vt + (size_t)(d0 + r) * 2048 + s0 + tx) = o;
    }
  }
}

// ---------------------------------------------------------------------------
// Flash attention v7 (R7 — unchanged): 256 pair-blocks, 512 threads, 144 KiB
// LDS forces 1 block/CU; complementary q-tile pair per block = exactly 17
// iterations per CU; double-buffered K/V, 2 barriers/iter, counted vmcnt.
// ---------------------------------------------------------------------------
__global__ __launch_bounds__(512, 1) void flash_attn(
    const u16* __restrict__ QKVp, const u16* __restrict__ VTp,
    u16* __restrict__ ATp) {
  const int bid = (int)blockIdx.x;              // 256 blocks
  const int h   = bid & 15;
  const int g   = bid >> 4;                     // 0..15

  __shared__ __align__(16) u16 Ks[2][128][128]; // 64 KB
  __shared__ __align__(16) u16 Vs[2][128][128]; // 64 KB
  __shared__ __align__(16) u16 Ps[64][128];     // 16 KB

  const int t = threadIdx.x;
  const int lane = t & 63;
  const int wave = t >> 6;                      // 0..7
  const int quad = lane >> 4;
  const int mrow = lane & 15;
  const int sw   = mrow & 7;
  const int wmS = (wave & 1) << 5;
  const int wnS = (wave >> 1) << 5;
  const int wmV = (wave >> 1) << 5;
  const int wnP = (wave & 1) << 5;

  const int r4  = lane >> 4;
  const int seg = lane & 15;
  const int c0 = ((seg ^ r4) << 3);
  const int c4 = ((seg ^ (r4 + 4)) << 3);

  const u16* kbase = QKVp + 2048 + (h << 7);
  const u16* vbase = VTp + (size_t)(h << 7) * 2048;

#define STAGE_K(nb, kt)                                                        \
  do {                                                                         \
    int rr0_ = wave << 4;                                                      \
    _Pragma("unroll") for (int ii_ = 0; ii_ < 4; ii_++) {                      \
      int rr_ = rr0_ + (ii_ << 2);                                             \
      GLOAD_LDS16(kbase + (size_t)(((kt) << 7) + rr_ + r4) * 6144 +            \
                      ((ii_ & 1) ? c4 : c0),                                   \
                  &Ks[nb][rr_][0]);                                            \
    }                                                                          \
  } while (0)
#define STAGE_V(nb, kt)                                                        \
  do {                                                                         \
    int rr0_ = wave << 4;                                                      \
    _Pragma("unroll") for (int ii_ = 0; ii_ < 4; ii_++) {                      \
      int rr_ = rr0_ + (ii_ << 2);                                             \
      GLOAD_LDS16(vbase + (size_t)(rr_ + r4) * 2048 + ((kt) << 7) +            \
                      ((ii_ & 1) ? c4 : c0),                                   \
                  &Vs[nb][rr_][0]);                                            \
    }                                                                          \
  } while (0)

  const short8 ones = {0x3F80, 0x3F80, 0x3F80, 0x3F80,
                       0x3F80, 0x3F80, 0x3F80, 0x3F80};   // bf16 1.0 x8
  const float C2 = 23.083120654223414f;         // 16*log2(e)

  for (int pass = 0; pass < 2; pass++) {
    const int qsub  = pass ? g : 31 - g;        // heavy tile first
    const int q0    = qsub << 6;
    const int ktmax = qsub >> 1;
    const u16* qbase = QKVp + (size_t)q0 * 6144 + (h << 7);

    short8 aq[2][4];
#pragma unroll
    for (int i = 0; i < 2; i++)
#pragma unroll
      for (int kk = 0; kk < 4; kk++)
        aq[i][kk] = *(const short8*)(qbase +
                        (size_t)(wmS + (i << 4) + mrow) * 6144 +
                        (kk << 5) + (quad << 3));

    floatx4 Oa[2][2] = {};
    floatx4 Oa1[2] = {};

    STAGE_K(0, 0);
    STAGE_V(0, 0);
    WAITV(4);
    BAR;

    for (int kt = 0; kt <= ktmax; kt++) {
      const int b = kt & 1, nb = b ^ 1;

      floatx4 sa[2][2] = {};
#pragma unroll
      for (int kk = 0; kk < 4; kk++) {
        short8 bk[2];
#pragma unroll
        for (int j = 0; j < 2; j++)
          bk[j] = *(const short8*)&Ks[b][wnS + (j << 4) + mrow]
                      [(((kk << 2) | quad) ^ sw) << 3];
        __builtin_amdgcn_s_setprio(1);
#pragma unroll
        for (int i = 0; i < 2; i++)
#pragma unroll
          for (int j = 0; j < 2; j++)
            sa[i][j] = __builtin_amdgcn_mfma_f32_16x16x32_bf16(
                aq[i][kk], bk[j], sa[i][j], 0, 0, 0);
        __builtin_amdgcn_s_setprio(0);
      }

      if (kt < ktmax) {
        STAGE_K(nb, kt + 1);
        STAGE_V(nb, kt + 1);
      }

      if (kt == ktmax) {
#pragma unroll
        for (int i = 0; i < 2; i++)
#pragma unroll
          for (int j = 0; j < 2; j++)
#pragma unroll
            for (int r = 0; r < 4; r++) {
              int ql = q0 + wmS + (i << 4) + (quad << 2) + r;
              int sl = (kt << 7) + wnS + (j << 4) + mrow;
              if (sl > ql) sa[i][j][r] = -1e30f;
            }
      }
#pragma unroll
      for (int i = 0; i < 2; i++)
#pragma unroll
        for (int j = 0; j < 2; j++)
#pragma unroll
          for (int r = 0; r < 4; r++) {
            int row = wmS + (i << 4) + (quad << 2) + r;
            int col = wnS + (j << 4) + mrow;
            Ps[row][((((col >> 3) ^ (row & 7)) << 3) | (col & 7))] =
                f2bf(EXP2F(sa[i][j][r] - C2));
          }
      WAITL;
      if (kt < ktmax) WAITV(8);
      else            WAITV(0);
      BAR;  // B1: Ps visible + V(kt) resident

#pragma unroll
      for (int kk = 0; kk < 4; kk++) {
        short8 av[2], bp[2];
#pragma unroll
        for (int i = 0; i < 2; i++)
          av[i] = *(const short8*)&Vs[b][wmV + (i << 4) + mrow]
                      [(((kk << 2) | quad) ^ sw) << 3];
#pragma unroll
        for (int j = 0; j < 2; j++)
          bp[j] = *(const short8*)&Ps[wnP + (j << 4) + mrow]
                      [(((kk << 2) | quad) ^ sw) << 3];
        __builtin_amdgcn_s_setprio(1);
#pragma unroll
        for (int i = 0; i < 2; i++)
#pragma unroll
          for (int j = 0; j < 2; j++)
            Oa[i][j] = __builtin_amdgcn_mfma_f32_16x16x32_bf16(
                av[i], bp[j], Oa[i][j], 0, 0, 0);
#pragma unroll
        for (int j = 0; j < 2; j++)
          Oa1[j] = __builtin_amdgcn_mfma_f32_16x16x32_bf16(
              ones, bp[j], Oa1[j], 0, 0, 0);
        __builtin_amdgcn_s_setprio(0);
      }
      if (kt < ktmax) WAITV(4);
      BAR;  // B2
    }

    float linv[2];
#pragma unroll
    for (int j = 0; j < 2; j++) linv[j] = 1.f / Oa1[j][0];
#pragma unroll
    for (int i = 0; i < 2; i++) {
      int drow = (h << 7) + wmV + (i << 4) + (quad << 2);
#pragma unroll
      for (int j = 0; j < 2; j++) {
        int col = q0 + wnP + (j << 4) + mrow;
#pragma unroll
        for (int r = 0; r < 4; r++)
          ATp[(size_t)(drow + r) * 2048 + col] = f2bf(Oa[i][j][r] * linv[j]);
      }
    }
  }
#undef STAGE_K
#undef STAGE_V
}

// ---------------------------------------------------------------------------
// Orchestration:
//   QKV = BT256x192(x, [wq;wk;wv]); rope(Q,K) + VT = transpose(V) [merged];
//   AT  = flash_attn (256 pair-blocks, 1/CU forced);
//   out = gemm_out(AT, wo)  [128^2 tiles, 256 blocks, fp32 direct].
// ---------------------------------------------------------------------------
extern "C" void kernel_launch(void* const* d_in, const int* in_sizes, int n_in,
                              void* d_out, int out_size, void* d_ws, size_t ws_size,
                              hipStream_t stream) {
  const float* x  = (const float*)d_in[0];
  const float* fc = (const float*)d_in[1];
  const float* fs = (const float*)d_in[2];
  const float* wq = (const float*)d_in[4];
  const float* wk = (const float*)d_in[5];
  const float* wv = (const float*)d_in[6];
  const float* wo = (const float*)d_in[7];
  float* out = (float*)d_out;

  char* ws = (char*)d_ws;
  const size_t MB = 1024 * 1024;
  u16*   XB   = (u16*)(ws + 0 * MB);
  u16*   WQKV = (u16*)(ws + 8 * MB);     // [wq;wk;wv] 6144x2048
  u16*   WOb  = (u16*)(ws + 32 * MB);
  u16*   QKV  = (u16*)(ws + 40 * MB);    // [s][6144]
  u16*   VT   = (u16*)(ws + 64 * MB);    // [d][s]
  u16*   AT   = (u16*)(ws + 72 * MB);    // [(h*128+d)][q]

  dim3 blk(256);
  cvt_all<<<dim3(4096, 5), blk, 0, stream>>>(
      (const floatx4*)x, (const floatx4*)wq, (const floatx4*)wk,
      (const floatx4*)wv, (const floatx4*)wo,
      (ushortx4*)XB, (ushortx4*)WQKV, (ushortx4*)WOb);

  // fused QKV projection: M=2048, N=6144, K=2048 — 256x192 tiles,
  // 8 x 32 = 256 blocks (exactly 1/CU), 512 threads.
  gemm256_bt<<<dim3(256), dim3(512), 0, stream>>>(XB, WQKV, QKV,
                                                  6144, 2048, 2048, 2048, 6144);

  // rope(Q,K) [16384 blocks] + transpose V -> VT [1024 blocks], one launch
  rope_trans<<<dim3(17408), blk, 0, stream>>>(QKV, fc, fs, VT);

  // 256 pair-blocks, 512 threads, 144 KiB LDS (forces 1 block/CU)
  flash_attn<<<dim3(256), dim3(512), 0, stream>>>(QKV, VT, AT);

  // final projection: out[r][j] = sum_q AT[r][q] * wo[j][q], fp32 direct
  gemm_out<<<dim3(256), blk, 0, stream>>>(AT, WOb, out);
}